// Round 4
// baseline (371.308 us; speedup 1.0000x reference)
//
#include <hip/hip_runtime.h>
#include <hip/hip_bf16.h>
#include <stdint.h>

typedef __attribute__((ext_vector_type(8))) short short8;
typedef __attribute__((ext_vector_type(4))) short short4v;
typedef __attribute__((ext_vector_type(4))) float floatx4;

#define B_   16
#define N_   1024
#define C_   768
#define H_   12
#define D_   64
#define K_   768
// (1/sqrt(64)) * log2(e): folds softmax scale AND natural->base2 exp into Q
#define QSCALE 0.18033688011112042f

__device__ __forceinline__ short f2bf(float f) {
    __hip_bfloat16 h = __float2bfloat16(f);
    short s; __builtin_memcpy(&s, &h, 2); return s;
}

// load 8 consecutive fp32, round to bf16, pack as short8 (MFMA fragment order)
__device__ __forceinline__ short8 ld8_f32(const float* p) {
    float4 u = *(const float4*)p;
    float4 v = *(const float4*)(p + 4);
    short8 r;
    r[0] = f2bf(u.x); r[1] = f2bf(u.y); r[2] = f2bf(u.z); r[3] = f2bf(u.w);
    r[4] = f2bf(v.x); r[5] = f2bf(v.y); r[6] = f2bf(v.z); r[7] = f2bf(v.w);
    return r;
}

// ---------------------------------------------------------------------------
// GEMM  C[M,N] = A[M,K] * B[N,K]^T   (both K-major, 128x128 tile, BK=32)
// A dtype: MODE 0 -> fp32 (input x), MODE 1 -> bf16 (my o_ws). B always fp32.
// MODE 0 epilogue: scatter to q_ws [bh,n,d] (scaled), k_ws [bh,n,d],
//                  v_ws [bh,d,n] (transposed). MODE 1: +bias, fp32 out.
// ---------------------------------------------------------------------------
template<int MODE>
__global__ __launch_bounds__(256, 2)
void gemm_bt(const void* __restrict__ Ap, const float* __restrict__ Bm,
             const float* __restrict__ bias,
             short* __restrict__ q_ws, short* __restrict__ k_ws,
             short* __restrict__ v_ws, float* __restrict__ outp)
{
    __shared__ short Alds[128 * 32];
    __shared__ short Blds[128 * 32];
    const int tid  = threadIdx.x;
    const int wave = tid >> 6, lane = tid & 63;
    const int cl   = lane & 15, quad = lane >> 4;
    const int bm = blockIdx.x, bn = blockIdx.y;
    const int wm = (wave >> 1) * 64, wn = (wave & 1) * 64;

    const long Abase = (long)bm * 128 * K_;
    const long Bbase = (long)bn * 128 * K_;
    const int srow = tid >> 2;          // 0..63
    const int scol = (tid & 3) * 8;     // element offset within BK=32

    const floatx4 fzero = {0.f, 0.f, 0.f, 0.f};
    floatx4 acc[4][4];
    #pragma unroll
    for (int i = 0; i < 4; i++)
        #pragma unroll
        for (int j = 0; j < 4; j++) acc[i][j] = fzero;

    for (int kt = 0; kt < K_; kt += 32) {
        short8 a0, a1;
        if (MODE == 0) {
            const float* Af = (const float*)Ap;
            a0 = ld8_f32(Af + Abase + (long)srow * K_ + kt + scol);
            a1 = ld8_f32(Af + Abase + (long)(srow + 64) * K_ + kt + scol);
        } else {
            const short* As = (const short*)Ap;
            a0 = *(const short8*)(As + Abase + (long)srow * K_ + kt + scol);
            a1 = *(const short8*)(As + Abase + (long)(srow + 64) * K_ + kt + scol);
        }
        short8 b0 = ld8_f32(Bm + Bbase + (long)srow * K_ + kt + scol);
        short8 b1 = ld8_f32(Bm + Bbase + (long)(srow + 64) * K_ + kt + scol);
        __syncthreads();   // protect previous iteration's LDS readers
        *(short8*)(Alds + srow * 32 + scol)        = a0;
        *(short8*)(Alds + (srow + 64) * 32 + scol) = a1;
        *(short8*)(Blds + srow * 32 + scol)        = b0;
        *(short8*)(Blds + (srow + 64) * 32 + scol) = b1;
        __syncthreads();

        short8 af[4], bf[4];
        #pragma unroll
        for (int i = 0; i < 4; i++)
            af[i] = *(const short8*)(Alds + (wm + i * 16 + cl) * 32 + quad * 8);
        #pragma unroll
        for (int j = 0; j < 4; j++)
            bf[j] = *(const short8*)(Blds + (wn + j * 16 + cl) * 32 + quad * 8);
        #pragma unroll
        for (int i = 0; i < 4; i++)
            #pragma unroll
            for (int j = 0; j < 4; j++)
                acc[i][j] = __builtin_amdgcn_mfma_f32_16x16x32_bf16(af[i], bf[j], acc[i][j], 0, 0, 0);
    }

    // epilogue.  C/D layout: row(m) = quad*4 + reg, col(n) = cl  [verified m89/m91]
    #pragma unroll
    for (int i = 0; i < 4; i++) {
        const int gm0 = bm * 128 + wm + i * 16 + quad * 4;  // token index (4 consecutive)
        #pragma unroll
        for (int j = 0; j < 4; j++) {
            const int gn = bn * 128 + wn + j * 16 + cl;     // output-feature index
            if (MODE == 0) {
                const int t   = bn / 6;          // 0=Q,1=K,2=V (block-uniform: 2304/128=18, 6 per type)
                const int rem = gn - t * 768;
                const int h   = rem >> 6, d = rem & 63;
                const int b   = gm0 >> 10;
                const int n0  = gm0 & 1023;
                const int bh  = b * H_ + h;
                if (t == 2) {
                    short4v pk;
                    #pragma unroll
                    for (int r = 0; r < 4; r++) pk[r] = f2bf(acc[i][j][r]);
                    *(short4v*)(v_ws + (((long)(bh * D_ + d)) << 10) + n0) = pk;   // [bh,d,n]
                } else {
                    short* dst = (t == 0) ? q_ws : k_ws;
                    const float sc = (t == 0) ? QSCALE : 1.0f;
                    #pragma unroll
                    for (int r = 0; r < 4; r++)
                        dst[((long)bh * N_ + (n0 + r)) * D_ + d] = f2bf(acc[i][j][r] * sc);
                }
            } else {
                const float bv = bias[gn];
                #pragma unroll
                for (int r = 0; r < 4; r++)
                    outp[(long)(gm0 + r) * C_ + gn] = acc[i][j][r] + bv;   // fp32 output
            }
        }
    }
}

// ---------------------------------------------------------------------------
// Flash attention: one block = one (b,h) x 64 Q-rows (4 waves x 16 rows).
// KV chunks of 128 staged in LDS; online softmax (base-2, scale folded in Q);
// P transposed C-layout -> A-layout through per-wave LDS (m120 pattern).
// ---------------------------------------------------------------------------
__global__ __launch_bounds__(256, 2)
void attn_fused(const short* __restrict__ q_ws, const short* __restrict__ k_ws,
                const short* __restrict__ v_ws, short* __restrict__ o_ws)
{
    __shared__ short Klds[128 * 72];      // [key][d], pad 64->72
    __shared__ short Vlds[64 * 136];      // [d][key], pad 128->136
    __shared__ short Plds[4][16 * 136];   // per-wave [qrow][key]

    const int tid  = threadIdx.x;
    const int wave = tid >> 6, lane = tid & 63;
    const int cl   = lane & 15, quad = lane >> 4;
    const int qt = blockIdx.x, bh = blockIdx.y;

    const long base = (long)bh * (N_ * D_);   // same elem count for [n,d] and [d,n]
    const int qrow = qt * 64 + wave * 16 + cl;

    // Q A-fragments, held for whole block: A[m=cl][k = s*32 + quad*8 + j]
    const short8 qf0 = *(const short8*)(q_ws + base + (long)qrow * D_ + quad * 8);
    const short8 qf1 = *(const short8*)(q_ws + base + (long)qrow * D_ + 32 + quad * 8);

    const floatx4 fzero = {0.f, 0.f, 0.f, 0.f};
    float m_r[4], l_r[4];
    floatx4 o_acc[4];                     // [dt]: row(q)=quad*4+r, col(d)=dt*16+cl
    #pragma unroll
    for (int r = 0; r < 4; r++) { m_r[r] = -1e30f; l_r[r] = 0.f; }
    #pragma unroll
    for (int dt = 0; dt < 4; dt++) o_acc[dt] = fzero;

    const int skey = tid >> 3, sseg = (tid & 7) * 8;   // K staging: row=key
    const int vd   = tid >> 4, vseg = (tid & 15) * 8;  // V staging: row=d
    short* pl = &Plds[wave][0];

    for (int kc = 0; kc < N_; kc += 128) {
        short8 kst[4], vst[4];
        #pragma unroll
        for (int p = 0; p < 4; p++) {
            kst[p] = *(const short8*)(k_ws + base + (long)(kc + p * 32 + skey) * D_ + sseg);
            vst[p] = *(const short8*)(v_ws + base + (long)(p * 16 + vd) * N_ + kc + vseg);
        }
        __syncthreads();
        #pragma unroll
        for (int p = 0; p < 4; p++) {
            *(short8*)(Klds + (p * 32 + skey) * 72 + sseg)  = kst[p];
            *(short8*)(Vlds + (p * 16 + vd) * 136 + vseg)   = vst[p];
        }
        __syncthreads();

        // S = Q*K^T for 128 keys: 8 col-tiles x 2 k-steps
        floatx4 s[8];
        #pragma unroll
        for (int nt = 0; nt < 8; nt++) {
            short8 kf0 = *(const short8*)(Klds + (nt * 16 + cl) * 72 + quad * 8);
            short8 kf1 = *(const short8*)(Klds + (nt * 16 + cl) * 72 + 32 + quad * 8);
            floatx4 t4 = fzero;
            t4 = __builtin_amdgcn_mfma_f32_16x16x32_bf16(qf0, kf0, t4, 0, 0, 0);
            t4 = __builtin_amdgcn_mfma_f32_16x16x32_bf16(qf1, kf1, t4, 0, 0, 0);
            s[nt] = t4;
        }

        // online softmax; per-lane rows = quad*4 + r, cols = nt*16 + cl
        float alpha[4];
        #pragma unroll
        for (int r = 0; r < 4; r++) {
            float v = s[0][r];
            #pragma unroll
            for (int nt = 1; nt < 8; nt++) v = fmaxf(v, s[nt][r]);
            v = fmaxf(v, __shfl_xor(v, 1));
            v = fmaxf(v, __shfl_xor(v, 2));
            v = fmaxf(v, __shfl_xor(v, 4));
            v = fmaxf(v, __shfl_xor(v, 8));
            const float mn = fmaxf(m_r[r], v);
            alpha[r] = __builtin_amdgcn_exp2f(m_r[r] - mn);
            m_r[r] = mn;
            l_r[r] *= alpha[r];
        }
        #pragma unroll
        for (int nt = 0; nt < 8; nt++) {
            #pragma unroll
            for (int r = 0; r < 4; r++) {
                const float p = __builtin_amdgcn_exp2f(s[nt][r] - m_r[r]);
                l_r[r] += p;   // per-lane partial; cross-lane reduce deferred to end
                pl[(quad * 4 + r) * 136 + nt * 16 + cl] = f2bf(p);
            }
        }
        #pragma unroll
        for (int dt = 0; dt < 4; dt++) {
            o_acc[dt][0] *= alpha[0]; o_acc[dt][1] *= alpha[1];
            o_acc[dt][2] *= alpha[2]; o_acc[dt][3] *= alpha[3];
        }
        asm volatile("" ::: "memory");   // P writes (short) vs short8 reads: defeat TBAA reordering

        // O += P * V : A=P from Plds [m=cl][k=ks*32+quad*8+j], B=V from Vlds [n=d][k]
        #pragma unroll
        for (int ks = 0; ks < 4; ks++) {
            short8 pf = *(const short8*)(pl + cl * 136 + ks * 32 + quad * 8);
            #pragma unroll
            for (int dt = 0; dt < 4; dt++) {
                short8 vf = *(const short8*)(Vlds + (dt * 16 + cl) * 136 + ks * 32 + quad * 8);
                o_acc[dt] = __builtin_amdgcn_mfma_f32_16x16x32_bf16(pf, vf, o_acc[dt], 0, 0, 0);
            }
        }
        asm volatile("" ::: "memory");   // keep next chunk's P writes after these reads
    }

    // final: reduce l across the quad's 16 lanes, normalize, store [b,n,c]
    #pragma unroll
    for (int r = 0; r < 4; r++) {
        float v = l_r[r];
        v += __shfl_xor(v, 1); v += __shfl_xor(v, 2);
        v += __shfl_xor(v, 4); v += __shfl_xor(v, 8);
        l_r[r] = 1.0f / v;
    }
    const int b = bh / H_, h = bh - b * H_;
    const int nrow = qt * 64 + wave * 16 + quad * 4;
    #pragma unroll
    for (int dt = 0; dt < 4; dt++) {
        const int c = h * D_ + dt * 16 + cl;
        #pragma unroll
        for (int r = 0; r < 4; r++)
            o_ws[((long)(b * N_ + nrow + r)) * C_ + c] = f2bf(o_acc[dt][r] * l_r[r]);
    }
}

extern "C" void kernel_launch(void* const* d_in, const int* in_sizes, int n_in,
                              void* d_out, int out_size, void* d_ws, size_t ws_size,
                              hipStream_t stream)
{
    const float* x      = (const float*)d_in[0];   // [16,1024,768] fp32
    const float* w_qkv  = (const float*)d_in[1];   // [2304,768]   fp32
    const float* w_proj = (const float*)d_in[2];   // [768,768]    fp32
    const float* b_proj = (const float*)d_in[3];   // [768]        fp32
    float* out = (float*)d_out;                    // [16,1024,768] fp32 (reference output dtype)

    const long SZ = (long)B_ * N_ * C_;            // 12,582,912 elems = 25.2 MB bf16
    short* q_ws = (short*)d_ws;                    // [bh, n, d] (pre-scaled)
    short* k_ws = q_ws + SZ;                       // [bh, n, d]
    short* v_ws = k_ws + SZ;                       // [bh, d, n] (transposed)
    short* o_ws = v_ws + SZ;                       // [b, n, c] bf16

    gemm_bt<0><<<dim3(128, 18), 256, 0, stream>>>(x, w_qkv, nullptr, q_ws, k_ws, v_ws, nullptr);
    attn_fused<<<dim3(16, 192), 256, 0, stream>>>(q_ws, k_ws, v_ws, o_ws);
    gemm_bt<1><<<dim3(128, 6), 256, 0, stream>>>(o_ws, w_proj, b_proj, nullptr, nullptr, nullptr, out);
}

// Round 5
// 321.575 us; speedup vs baseline: 1.1547x; 1.1547x over previous
//
#include <hip/hip_runtime.h>
#include <hip/hip_bf16.h>
#include <stdint.h>

typedef __attribute__((ext_vector_type(8))) short short8;
typedef __attribute__((ext_vector_type(4))) short short4v;
typedef __attribute__((ext_vector_type(4))) float floatx4;

#define B_   16
#define N_   1024
#define C_   768
#define H_   12
#define D_   64
#define K_   768
// (1/sqrt(64)) * log2(e): folds softmax scale AND natural->base2 exp into Q
#define QSCALE 0.18033688011112042f

__device__ __forceinline__ short f2bf(float f) {
    __hip_bfloat16 h = __float2bfloat16(f);
    short s; __builtin_memcpy(&s, &h, 2); return s;
}

// async global->LDS DMA, 16 B per lane. lds dest must be wave-uniform base;
// HW writes lane i at base + i*16 (m97/m104).
__device__ __forceinline__ void gl_lds16(const void* g, void* l) {
    __builtin_amdgcn_global_load_lds(
        (const __attribute__((address_space(1))) unsigned int*)g,
        (__attribute__((address_space(3))) unsigned int*)l, 16, 0, 0);
}

// ---------------------------------------------------------------------------
// fp32 -> bf16 pack, 8 elems/thread
// ---------------------------------------------------------------------------
__global__ void cvt_bf16(const float* __restrict__ in, short* __restrict__ out, int n8)
{
    const int i = blockIdx.x * 256 + threadIdx.x;
    if (i >= n8) return;
    const float4* p = (const float4*)in + 2 * (long)i;
    const float4 u = p[0], v = p[1];
    short8 r;
    r[0] = f2bf(u.x); r[1] = f2bf(u.y); r[2] = f2bf(u.z); r[3] = f2bf(u.w);
    r[4] = f2bf(v.x); r[5] = f2bf(v.y); r[6] = f2bf(v.z); r[7] = f2bf(v.w);
    *((short8*)out + i) = r;
}

// ---------------------------------------------------------------------------
// GEMM  C[M,N] = A[M,K] * B[N,K]^T  (bf16, K-major, 128x128 tile, BK=32,
// global_load_lds staging — m97 structure).
// MODE 0: QKV epilogue -> q_ws [bh,n,d] (scaled), k_ws [bh,n,d], v_ws [bh,d,n]
// MODE 1: proj epilogue -> +bias, fp32 out
// ---------------------------------------------------------------------------
template<int MODE>
__global__ __launch_bounds__(256, 2)
void gemm_bt(const short* __restrict__ A, const short* __restrict__ Bm,
             const float* __restrict__ bias,
             short* __restrict__ q_ws, short* __restrict__ k_ws,
             short* __restrict__ v_ws, float* __restrict__ outp)
{
    __shared__ short Alds[128 * 32];
    __shared__ short Blds[128 * 32];
    const int tid  = threadIdx.x;
    const int wave = tid >> 6, lane = tid & 63;
    const int cl   = lane & 15, quad = lane >> 4;
    const int bm = blockIdx.x, bn = blockIdx.y;
    const int wm = (wave >> 1) * 64, wn = (wave & 1) * 64;

    // staging: thread t covers global row t>>2 (+64), 8-elem seg (t&3)*8.
    // LDS slot = t*8 shorts == row-major [128][32] position (contiguous in lane order).
    const short* Ag = A  + (long)bm * 128 * K_ + (long)(tid >> 2) * K_ + (tid & 3) * 8;
    const short* Bg = Bm + (long)bn * 128 * K_ + (long)(tid >> 2) * K_ + (tid & 3) * 8;
    short* la = Alds + (tid & 0xC0) * 8;   // wave-uniform base
    short* lb = Blds + (tid & 0xC0) * 8;

    const floatx4 fzero = {0.f, 0.f, 0.f, 0.f};
    floatx4 acc[4][4];
    #pragma unroll
    for (int i = 0; i < 4; i++)
        #pragma unroll
        for (int j = 0; j < 4; j++) acc[i][j] = fzero;

    for (int kt = 0; kt < K_; kt += 32) {
        __syncthreads();                    // previous iter's readers done
        gl_lds16(Ag + kt,            la);
        gl_lds16(Ag + kt + 64 * K_,  la + 2048);
        gl_lds16(Bg + kt,            lb);
        gl_lds16(Bg + kt + 64 * K_,  lb + 2048);
        __syncthreads();                    // drains vmcnt (DMA complete)

        short8 af[4], bf[4];
        #pragma unroll
        for (int i = 0; i < 4; i++)
            af[i] = *(const short8*)(Alds + (wm + i * 16 + cl) * 32 + quad * 8);
        #pragma unroll
        for (int j = 0; j < 4; j++)
            bf[j] = *(const short8*)(Blds + (wn + j * 16 + cl) * 32 + quad * 8);
        #pragma unroll
        for (int i = 0; i < 4; i++)
            #pragma unroll
            for (int j = 0; j < 4; j++)
                acc[i][j] = __builtin_amdgcn_mfma_f32_16x16x32_bf16(af[i], bf[j], acc[i][j], 0, 0, 0);
    }

    // epilogue.  C/D layout: row(m) = quad*4 + reg, col(n) = cl  [m89/m91]
    #pragma unroll
    for (int i = 0; i < 4; i++) {
        const int gm0 = bm * 128 + wm + i * 16 + quad * 4;
        #pragma unroll
        for (int j = 0; j < 4; j++) {
            const int gn = bn * 128 + wn + j * 16 + cl;
            if (MODE == 0) {
                const int t   = bn / 6;          // 0=Q,1=K,2=V (block-uniform)
                const int rem = gn - t * 768;
                const int h   = rem >> 6, d = rem & 63;
                const int b   = gm0 >> 10;
                const int n0  = gm0 & 1023;
                const int bh  = b * H_ + h;
                if (t == 2) {
                    short4v pk;
                    #pragma unroll
                    for (int r = 0; r < 4; r++) pk[r] = f2bf(acc[i][j][r]);
                    *(short4v*)(v_ws + (((long)(bh * D_ + d)) << 10) + n0) = pk;   // [bh,d,n]
                } else {
                    short* dst = (t == 0) ? q_ws : k_ws;
                    const float sc = (t == 0) ? QSCALE : 1.0f;
                    #pragma unroll
                    for (int r = 0; r < 4; r++)
                        dst[((long)bh * N_ + (n0 + r)) * D_ + d] = f2bf(acc[i][j][r] * sc);
                }
            } else {
                const float bv = bias[gn];
                #pragma unroll
                for (int r = 0; r < 4; r++)
                    outp[(long)(gm0 + r) * C_ + gn] = acc[i][j][r] + bv;   // fp32 out
            }
        }
    }
}

// ---------------------------------------------------------------------------
// Flash attention: one block = one (b,h) x 128 Q-rows (4 waves x 2 m-tiles).
// XCD-swizzled so all 8 q-tiles of a bh land on one XCD (KV stays in its L2).
// KV chunks of 128 staged in LDS; online softmax (base-2, scale in Q);
// P transposed C->A layout through per-wave LDS, buffer reused across m-tiles.
// ---------------------------------------------------------------------------
__global__ __launch_bounds__(256, 2)
void attn_fused(const short* __restrict__ q_ws, const short* __restrict__ k_ws,
                const short* __restrict__ v_ws, short* __restrict__ o_ws)
{
    __shared__ short Klds[128 * 72];      // [key][d], pad 64->72
    __shared__ short Vlds[64 * 136];      // [d][key], pad 128->136
    __shared__ short Plds[4][16 * 136];   // per-wave [qrow][key], reused per m-tile

    const int tid  = threadIdx.x;
    const int wave = tid >> 6, lane = tid & 63;
    const int cl   = lane & 15, quad = lane >> 4;

    // XCD swizzle: linear%8 = XCD (round-robin dispatch assumption — perf only).
    // Each XCD owns bh in [24*xcd, 24*xcd+24), qt-minor -> resident window ~12 bh
    // = 3 MB KV, fits 4 MB per-XCD L2.
    const int linear = blockIdx.y * 8 + blockIdx.x;   // gridDim = (8, 192)
    const int xcd = linear & 7, slot = linear >> 3;   // slot 0..191
    const int bh  = xcd * 24 + (slot >> 3);
    const int qt  = slot & 7;

    const long base = (long)bh * (N_ * D_);
    const int  qr0  = qt * 128 + wave * 32 + cl;

    // Q A-fragments for both m-tiles: A[m=cl][k = ks*32 + quad*8 + j]
    short8 qf[2][2];
    #pragma unroll
    for (int mt = 0; mt < 2; mt++) {
        qf[mt][0] = *(const short8*)(q_ws + base + (long)(qr0 + mt * 16) * D_ + quad * 8);
        qf[mt][1] = *(const short8*)(q_ws + base + (long)(qr0 + mt * 16) * D_ + 32 + quad * 8);
    }

    const floatx4 fzero = {0.f, 0.f, 0.f, 0.f};
    float m_r[2][4], l_r[2][4];
    floatx4 o_acc[2][4];                  // [mt][dt]: row=quad*4+r, col=dt*16+cl
    #pragma unroll
    for (int mt = 0; mt < 2; mt++)
        #pragma unroll
        for (int r = 0; r < 4; r++) {
            m_r[mt][r] = -1e30f; l_r[mt][r] = 0.f; o_acc[mt][r] = fzero;
        }

    const int skey = tid >> 3, sseg = (tid & 7) * 8;   // K staging: row=key
    const int vd   = tid >> 4, vseg = (tid & 15) * 8;  // V staging: row=d
    short* pl = &Plds[wave][0];

    for (int kc = 0; kc < N_; kc += 128) {
        short8 kst[4], vst[4];
        #pragma unroll
        for (int p = 0; p < 4; p++) {
            kst[p] = *(const short8*)(k_ws + base + (long)(kc + p * 32 + skey) * D_ + sseg);
            vst[p] = *(const short8*)(v_ws + base + (long)(p * 16 + vd) * N_ + kc + vseg);
        }
        __syncthreads();
        #pragma unroll
        for (int p = 0; p < 4; p++) {
            *(short8*)(Klds + (p * 32 + skey) * 72 + sseg) = kst[p];
            *(short8*)(Vlds + (p * 16 + vd) * 136 + vseg)  = vst[p];
        }
        __syncthreads();

        #pragma unroll
        for (int mt = 0; mt < 2; mt++) {
            // S = Q*K^T for 128 keys: 8 col-tiles x 2 k-steps
            floatx4 s[8];
            #pragma unroll
            for (int nt = 0; nt < 8; nt++) {
                short8 kf0 = *(const short8*)(Klds + (nt * 16 + cl) * 72 + quad * 8);
                short8 kf1 = *(const short8*)(Klds + (nt * 16 + cl) * 72 + 32 + quad * 8);
                floatx4 t4 = fzero;
                t4 = __builtin_amdgcn_mfma_f32_16x16x32_bf16(qf[mt][0], kf0, t4, 0, 0, 0);
                t4 = __builtin_amdgcn_mfma_f32_16x16x32_bf16(qf[mt][1], kf1, t4, 0, 0, 0);
                s[nt] = t4;
            }

            // online softmax; rows = quad*4 + r, cols = nt*16 + cl
            float alpha[4];
            #pragma unroll
            for (int r = 0; r < 4; r++) {
                float v = s[0][r];
                #pragma unroll
                for (int nt = 1; nt < 8; nt++) v = fmaxf(v, s[nt][r]);
                v = fmaxf(v, __shfl_xor(v, 1));
                v = fmaxf(v, __shfl_xor(v, 2));
                v = fmaxf(v, __shfl_xor(v, 4));
                v = fmaxf(v, __shfl_xor(v, 8));
                const float mn = fmaxf(m_r[mt][r], v);
                alpha[r] = __builtin_amdgcn_exp2f(m_r[mt][r] - mn);
                m_r[mt][r] = mn;
                l_r[mt][r] *= alpha[r];
            }
            #pragma unroll
            for (int nt = 0; nt < 8; nt++) {
                #pragma unroll
                for (int r = 0; r < 4; r++) {
                    const float p = __builtin_amdgcn_exp2f(s[nt][r] - m_r[mt][r]);
                    l_r[mt][r] += p;   // per-lane partial; cross-lane reduce at end
                    pl[(quad * 4 + r) * 136 + nt * 16 + cl] = f2bf(p);
                }
            }
            #pragma unroll
            for (int dt = 0; dt < 4; dt++) {
                o_acc[mt][dt][0] *= alpha[0]; o_acc[mt][dt][1] *= alpha[1];
                o_acc[mt][dt][2] *= alpha[2]; o_acc[mt][dt][3] *= alpha[3];
            }
            asm volatile("" ::: "memory");   // order P writes before P reads

            // O += P*V : A=P [m=cl][k], B=V [n=d][k]
            #pragma unroll
            for (int ks = 0; ks < 4; ks++) {
                short8 pf = *(const short8*)(pl + cl * 136 + ks * 32 + quad * 8);
                #pragma unroll
                for (int dt = 0; dt < 4; dt++) {
                    short8 vf = *(const short8*)(Vlds + (dt * 16 + cl) * 136 + ks * 32 + quad * 8);
                    o_acc[mt][dt] = __builtin_amdgcn_mfma_f32_16x16x32_bf16(pf, vf, o_acc[mt][dt], 0, 0, 0);
                }
            }
            asm volatile("" ::: "memory");   // P reads done before next mt's writes
        }
    }

    // finalize: reduce l across the quad's 16 lanes, normalize, store [b,n,c]
    const int b = bh / H_, h = bh - b * H_;
    #pragma unroll
    for (int mt = 0; mt < 2; mt++) {
        #pragma unroll
        for (int r = 0; r < 4; r++) {
            float v = l_r[mt][r];
            v += __shfl_xor(v, 1); v += __shfl_xor(v, 2);
            v += __shfl_xor(v, 4); v += __shfl_xor(v, 8);
            l_r[mt][r] = 1.0f / v;
        }
        const int nrow = qt * 128 + wave * 32 + mt * 16 + quad * 4;
        #pragma unroll
        for (int dt = 0; dt < 4; dt++) {
            const int c = h * D_ + dt * 16 + cl;
            #pragma unroll
            for (int r = 0; r < 4; r++)
                o_ws[((long)(b * N_ + nrow + r)) * C_ + c] = f2bf(o_acc[mt][dt][r] * l_r[mt][r]);
        }
    }
}

extern "C" void kernel_launch(void* const* d_in, const int* in_sizes, int n_in,
                              void* d_out, int out_size, void* d_ws, size_t ws_size,
                              hipStream_t stream)
{
    const float* x      = (const float*)d_in[0];   // [16,1024,768] fp32
    const float* w_qkv  = (const float*)d_in[1];   // [2304,768]   fp32
    const float* w_proj = (const float*)d_in[2];   // [768,768]    fp32
    const float* b_proj = (const float*)d_in[3];   // [768]        fp32
    float* out = (float*)d_out;                    // [16,1024,768] fp32

    const long SZ = (long)B_ * N_ * C_;            // 12,582,912 elems
    short* q_ws   = (short*)d_ws;                  // [bh, n, d] (pre-scaled)
    short* k_ws   = q_ws + SZ;                     // [bh, n, d]
    short* v_ws   = k_ws + SZ;                     // [bh, d, n] (transposed)
    short* x_bf   = v_ws + SZ;                     // x as bf16; later reused as o_ws
    short* o_ws   = x_bf;                          // alias: x dead after QKV GEMM
    short* wqkv_bf  = x_bf + SZ;                   // 1,769,472 elems
    short* wproj_bf = wqkv_bf + (long)3 * C_ * C_; // 589,824 elems

    cvt_bf16<<<dim3(6144), 256, 0, stream>>>(x,      x_bf,     (int)(SZ / 8));
    cvt_bf16<<<dim3(864),  256, 0, stream>>>(w_qkv,  wqkv_bf,  3 * C_ * C_ / 8);
    cvt_bf16<<<dim3(288),  256, 0, stream>>>(w_proj, wproj_bf, C_ * C_ / 8);

    gemm_bt<0><<<dim3(128, 18), 256, 0, stream>>>(x_bf, wqkv_bf, nullptr, q_ws, k_ws, v_ws, nullptr);
    attn_fused<<<dim3(8, 192), 256, 0, stream>>>(q_ws, k_ws, v_ws, o_ws);
    gemm_bt<1><<<dim3(128, 6), 256, 0, stream>>>(o_ws, wproj_bf, b_proj, nullptr, nullptr, nullptr, out);
}

// Round 6
// 313.186 us; speedup vs baseline: 1.1856x; 1.0268x over previous
//
#include <hip/hip_runtime.h>
#include <hip/hip_bf16.h>
#include <stdint.h>

typedef __attribute__((ext_vector_type(8))) short short8;
typedef __attribute__((ext_vector_type(4))) short short4v;
typedef __attribute__((ext_vector_type(4))) float floatx4;

#define B_   16
#define N_   1024
#define C_   768
#define H_   12
#define D_   64
#define K_   768
// (1/sqrt(64)) * log2(e): folds softmax scale AND natural->base2 exp into Q
#define QSCALE 0.18033688011112042f

__device__ __forceinline__ short f2bf(float f) {
    __hip_bfloat16 h = __float2bfloat16(f);
    short s; __builtin_memcpy(&s, &h, 2); return s;
}
// packed 2xf32 -> 2xbf16 (v_cvt_pk_bf16_f32 on gfx950)
__device__ __forceinline__ unsigned pk2bf(float a, float b) {
    __hip_bfloat162 h = __float22bfloat162_rn(make_float2(a, b));
    unsigned u; __builtin_memcpy(&u, &h, 4); return u;
}

// async global->LDS DMA, 16 B per lane; LDS dest = wave-uniform base + lane*16
__device__ __forceinline__ void gl_lds16(const void* g, void* l) {
    __builtin_amdgcn_global_load_lds(
        (const __attribute__((address_space(1))) unsigned int*)g,
        (__attribute__((address_space(3))) unsigned int*)l, 16, 0, 0);
}

// ---------------------------------------------------------------------------
// fused fp32->bf16 for x, w_qkv, w_proj (ranges are 256-block aligned)
// ---------------------------------------------------------------------------
#define N8_X  1572864   // (16*1024*768)/8
#define N8_WQ 221184    // (2304*768)/8
#define N8_WP 73728     // (768*768)/8
__global__ void cvt_all(const float* __restrict__ x, const float* __restrict__ wq,
                        const float* __restrict__ wp, short* __restrict__ xb,
                        short* __restrict__ wqb, short* __restrict__ wpb)
{
    long i = (long)blockIdx.x * 256 + threadIdx.x;   // 8-elem units
    const float* src; short* dst;
    if (i < N8_X)              { src = x;  dst = xb;  }
    else if (i < N8_X + N8_WQ) { src = wq; dst = wqb; i -= N8_X; }
    else                       { src = wp; dst = wpb; i -= (long)N8_X + N8_WQ; }
    const float4* p = (const float4*)src + 2 * i;
    const float4 u = p[0], v = p[1];
    short8 r;
    r[0] = f2bf(u.x); r[1] = f2bf(u.y); r[2] = f2bf(u.z); r[3] = f2bf(u.w);
    r[4] = f2bf(v.x); r[5] = f2bf(v.y); r[6] = f2bf(v.z); r[7] = f2bf(v.w);
    *((short8*)dst + i) = r;
}

// ---------------------------------------------------------------------------
// GEMM  C[M,N] = A[M,K] * B[N,K]^T  (bf16, K-major, 128x128 tile, BK=32,
// global_load_lds staging — m97 structure, 3 blocks/CU).
// MODE 0: QKV epilogue -> q_ws [bh,n,d] (scaled), k_ws [bh,n,d], v_ws [bh,d,n]
// MODE 1: proj epilogue -> +bias, fp32 out
// ---------------------------------------------------------------------------
template<int MODE>
__global__ __launch_bounds__(256, 3)
void gemm_bt(const short* __restrict__ A, const short* __restrict__ Bm,
             const float* __restrict__ bias,
             short* __restrict__ q_ws, short* __restrict__ k_ws,
             short* __restrict__ v_ws, float* __restrict__ outp)
{
    __shared__ short Alds[128 * 32];
    __shared__ short Blds[128 * 32];
    const int tid  = threadIdx.x;
    const int wave = tid >> 6, lane = tid & 63;
    const int cl   = lane & 15, quad = lane >> 4;
    const int bm = blockIdx.x, bn = blockIdx.y;
    const int wm = (wave >> 1) * 64, wn = (wave & 1) * 64;

    const short* Ag = A  + (long)bm * 128 * K_ + (long)(tid >> 2) * K_ + (tid & 3) * 8;
    const short* Bg = Bm + (long)bn * 128 * K_ + (long)(tid >> 2) * K_ + (tid & 3) * 8;
    short* la = Alds + (tid & 0xC0) * 8;   // wave-uniform base
    short* lb = Blds + (tid & 0xC0) * 8;

    const floatx4 fzero = {0.f, 0.f, 0.f, 0.f};
    floatx4 acc[4][4];
    #pragma unroll
    for (int i = 0; i < 4; i++)
        #pragma unroll
        for (int j = 0; j < 4; j++) acc[i][j] = fzero;

    for (int kt = 0; kt < K_; kt += 32) {
        __syncthreads();                    // previous iter's readers done
        gl_lds16(Ag + kt,            la);
        gl_lds16(Ag + kt + 64 * K_,  la + 2048);
        gl_lds16(Bg + kt,            lb);
        gl_lds16(Bg + kt + 64 * K_,  lb + 2048);
        __syncthreads();                    // drains vmcnt (DMA complete)

        short8 af[4], bf[4];
        #pragma unroll
        for (int i = 0; i < 4; i++)
            af[i] = *(const short8*)(Alds + (wm + i * 16 + cl) * 32 + quad * 8);
        #pragma unroll
        for (int j = 0; j < 4; j++)
            bf[j] = *(const short8*)(Blds + (wn + j * 16 + cl) * 32 + quad * 8);
        #pragma unroll
        for (int i = 0; i < 4; i++)
            #pragma unroll
            for (int j = 0; j < 4; j++)
                acc[i][j] = __builtin_amdgcn_mfma_f32_16x16x32_bf16(af[i], bf[j], acc[i][j], 0, 0, 0);
    }

    // epilogue.  C/D layout: row(m) = quad*4 + reg, col(n) = cl  [m89/m91]
    #pragma unroll
    for (int i = 0; i < 4; i++) {
        const int gm0 = bm * 128 + wm + i * 16 + quad * 4;
        #pragma unroll
        for (int j = 0; j < 4; j++) {
            const int gn = bn * 128 + wn + j * 16 + cl;
            if (MODE == 0) {
                const int t   = bn / 6;          // 0=Q,1=K,2=V (block-uniform)
                const int rem = gn - t * 768;
                const int h   = rem >> 6, d = rem & 63;
                const int b   = gm0 >> 10;
                const int n0  = gm0 & 1023;
                const int bh  = b * H_ + h;
                if (t == 2) {
                    short4v pk;
                    #pragma unroll
                    for (int r = 0; r < 4; r++) pk[r] = f2bf(acc[i][j][r]);
                    *(short4v*)(v_ws + (((long)(bh * D_ + d)) << 10) + n0) = pk;   // [bh,d,n]
                } else {
                    short* dst = (t == 0) ? q_ws : k_ws;
                    const float sc = (t == 0) ? QSCALE : 1.0f;
                    #pragma unroll
                    for (int r = 0; r < 4; r++)
                        dst[((long)bh * N_ + (n0 + r)) * D_ + d] = f2bf(acc[i][j][r] * sc);
                }
            } else {
                const float bv = bias[gn];
                #pragma unroll
                for (int r = 0; r < 4; r++)
                    outp[(long)(gm0 + r) * C_ + gn] = acc[i][j][r] + bv;   // fp32 out
            }
        }
    }
}

// ---------------------------------------------------------------------------
// Flash attention: one block = one (b,h) x 128 Q-rows (4 waves x 2 m-tiles).
// XCD-swizzled (KV stays in one XCD's L2). KV chunks of 128 in LDS.
// Key permutation k_virt = c*8 + nt (c=cl of the S-holder lane): keys are
// summation indices, so P and V use the same relabel. This makes each lane's
// 8 P-values per row CONTIGUOUS -> packed cvt + one ds_write_b128 per row
// (replaces 32 f2bf + 32 ds_write_b16 per m-tile). V is staged into k_virt
// order by a stride-16 gather (L2-resident).
// ---------------------------------------------------------------------------
__global__ __launch_bounds__(256, 3)
void attn_fused(const short* __restrict__ q_ws, const short* __restrict__ k_ws,
                const short* __restrict__ v_ws, short* __restrict__ o_ws)
{
    __shared__ short Klds[128 * 72];      // [key_phys][d], pad 64->72
    __shared__ short Vlds[64 * 136];      // [d][k_virt], pad 128->136
    __shared__ short Plds[4][16 * 136];   // per-wave [qrow][k_virt]

    const int tid  = threadIdx.x;
    const int wave = tid >> 6, lane = tid & 63;
    const int cl   = lane & 15, quad = lane >> 4;

    // XCD swizzle: each XCD owns 24 bh, qt-minor -> ~12 resident bh = 3 MB KV in L2
    const int linear = blockIdx.y * 8 + blockIdx.x;   // gridDim = (8, 192)
    const int xcd = linear & 7, slot = linear >> 3;
    const int bh  = xcd * 24 + (slot >> 3);
    const int qt  = slot & 7;

    const long base = (long)bh * (N_ * D_);
    const int  qr0  = qt * 128 + wave * 32 + cl;

    short8 qf[2][2];
    #pragma unroll
    for (int mt = 0; mt < 2; mt++) {
        qf[mt][0] = *(const short8*)(q_ws + base + (long)(qr0 + mt * 16) * D_ + quad * 8);
        qf[mt][1] = *(const short8*)(q_ws + base + (long)(qr0 + mt * 16) * D_ + 32 + quad * 8);
    }

    const floatx4 fzero = {0.f, 0.f, 0.f, 0.f};
    float m_r[2][4], l_r[2][4];
    floatx4 o_acc[2][4];
    #pragma unroll
    for (int mt = 0; mt < 2; mt++)
        #pragma unroll
        for (int r = 0; r < 4; r++) {
            m_r[mt][r] = -1e30f; l_r[mt][r] = 0.f; o_acc[mt][r] = fzero;
        }

    const int skey = tid >> 3, sseg = (tid & 7) * 8;   // K staging: row=key_phys
    const int vd   = tid >> 4, vc = tid & 15;          // V gather: row=d, c-group
    short* pl = &Plds[wave][0];

    for (int kc = 0; kc < N_; kc += 128) {
        short8 kst[4], vst[4];
        #pragma unroll
        for (int p = 0; p < 4; p++) {
            kst[p] = *(const short8*)(k_ws + base + (long)(kc + p * 32 + skey) * D_ + sseg);
            // gather k_virt = vc*8 + i  <->  k_phys = i*16 + vc
            #pragma unroll
            for (int i = 0; i < 8; i++)
                vst[p][i] = v_ws[base + (long)(p * 16 + vd) * N_ + kc + i * 16 + vc];
        }
        __syncthreads();
        #pragma unroll
        for (int p = 0; p < 4; p++) {
            *(short8*)(Klds + (p * 32 + skey) * 72 + sseg) = kst[p];
            *(short8*)(Vlds + (p * 16 + vd) * 136 + vc * 8) = vst[p];
        }
        __syncthreads();

        #pragma unroll
        for (int mt = 0; mt < 2; mt++) {
            // S = Q*K^T for 128 keys: lane cl holds cols k_phys = nt*16+cl
            floatx4 s[8];
            #pragma unroll
            for (int nt = 0; nt < 8; nt++) {
                short8 kf0 = *(const short8*)(Klds + (nt * 16 + cl) * 72 + quad * 8);
                short8 kf1 = *(const short8*)(Klds + (nt * 16 + cl) * 72 + 32 + quad * 8);
                floatx4 t4 = fzero;
                t4 = __builtin_amdgcn_mfma_f32_16x16x32_bf16(qf[mt][0], kf0, t4, 0, 0, 0);
                t4 = __builtin_amdgcn_mfma_f32_16x16x32_bf16(qf[mt][1], kf1, t4, 0, 0, 0);
                s[nt] = t4;
            }

            // online softmax; rows = quad*4 + r
            float alpha[4];
            #pragma unroll
            for (int r = 0; r < 4; r++) {
                float v = s[0][r];
                #pragma unroll
                for (int nt = 1; nt < 8; nt++) v = fmaxf(v, s[nt][r]);
                v = fmaxf(v, __shfl_xor(v, 1));
                v = fmaxf(v, __shfl_xor(v, 2));
                v = fmaxf(v, __shfl_xor(v, 4));
                v = fmaxf(v, __shfl_xor(v, 8));
                const float mn = fmaxf(m_r[mt][r], v);
                alpha[r] = __builtin_amdgcn_exp2f(m_r[mt][r] - mn);
                m_r[mt][r] = mn;
                l_r[mt][r] *= alpha[r];
            }
            // P: lane's 8 values per row are k_virt = cl*8 + nt -> contiguous
            #pragma unroll
            for (int r = 0; r < 4; r++) {
                float p0 = __builtin_amdgcn_exp2f(s[0][r] - m_r[mt][r]);
                float p1 = __builtin_amdgcn_exp2f(s[1][r] - m_r[mt][r]);
                float p2 = __builtin_amdgcn_exp2f(s[2][r] - m_r[mt][r]);
                float p3 = __builtin_amdgcn_exp2f(s[3][r] - m_r[mt][r]);
                float p4 = __builtin_amdgcn_exp2f(s[4][r] - m_r[mt][r]);
                float p5 = __builtin_amdgcn_exp2f(s[5][r] - m_r[mt][r]);
                float p6 = __builtin_amdgcn_exp2f(s[6][r] - m_r[mt][r]);
                float p7 = __builtin_amdgcn_exp2f(s[7][r] - m_r[mt][r]);
                l_r[mt][r] += ((p0 + p1) + (p2 + p3)) + ((p4 + p5) + (p6 + p7));
                uint4 pk = { pk2bf(p0, p1), pk2bf(p2, p3), pk2bf(p4, p5), pk2bf(p6, p7) };
                *(uint4*)(pl + (quad * 4 + r) * 136 + cl * 8) = pk;
            }
            #pragma unroll
            for (int dt = 0; dt < 4; dt++) {
                o_acc[mt][dt][0] *= alpha[0]; o_acc[mt][dt][1] *= alpha[1];
                o_acc[mt][dt][2] *= alpha[2]; o_acc[mt][dt][3] *= alpha[3];
            }
            asm volatile("" ::: "memory");   // order P writes before P reads

            // O += P*V over k_virt: A=P [m=cl][k], B=V [n=d][k]
            #pragma unroll
            for (int ks = 0; ks < 4; ks++) {
                short8 pf = *(const short8*)(pl + cl * 136 + ks * 32 + quad * 8);
                #pragma unroll
                for (int dt = 0; dt < 4; dt++) {
                    short8 vf = *(const short8*)(Vlds + (dt * 16 + cl) * 136 + ks * 32 + quad * 8);
                    o_acc[mt][dt] = __builtin_amdgcn_mfma_f32_16x16x32_bf16(pf, vf, o_acc[mt][dt], 0, 0, 0);
                }
            }
            asm volatile("" ::: "memory");   // P reads done before next mt's writes
        }
    }

    // finalize: reduce l across the quad's 16 lanes, normalize, store [b,n,c]
    const int b = bh / H_, h = bh - b * H_;
    #pragma unroll
    for (int mt = 0; mt < 2; mt++) {
        #pragma unroll
        for (int r = 0; r < 4; r++) {
            float v = l_r[mt][r];
            v += __shfl_xor(v, 1); v += __shfl_xor(v, 2);
            v += __shfl_xor(v, 4); v += __shfl_xor(v, 8);
            l_r[mt][r] = 1.0f / v;
        }
        const int nrow = qt * 128 + wave * 32 + mt * 16 + quad * 4;
        #pragma unroll
        for (int dt = 0; dt < 4; dt++) {
            const int c = h * D_ + dt * 16 + cl;
            #pragma unroll
            for (int r = 0; r < 4; r++)
                o_ws[((long)(b * N_ + nrow + r)) * C_ + c] = f2bf(o_acc[mt][dt][r] * l_r[mt][r]);
        }
    }
}

extern "C" void kernel_launch(void* const* d_in, const int* in_sizes, int n_in,
                              void* d_out, int out_size, void* d_ws, size_t ws_size,
                              hipStream_t stream)
{
    const float* x      = (const float*)d_in[0];
    const float* w_qkv  = (const float*)d_in[1];
    const float* w_proj = (const float*)d_in[2];
    const float* b_proj = (const float*)d_in[3];
    float* out = (float*)d_out;

    const long SZ = (long)B_ * N_ * C_;
    short* q_ws   = (short*)d_ws;                  // [bh, n, d] (pre-scaled)
    short* k_ws   = q_ws + SZ;                     // [bh, n, d]
    short* v_ws   = k_ws + SZ;                     // [bh, d, n] (transposed)
    short* x_bf   = v_ws + SZ;                     // x as bf16; reused as o_ws
    short* o_ws   = x_bf;                          // alias: x dead after QKV GEMM
    short* wqkv_bf  = x_bf + SZ;
    short* wproj_bf = wqkv_bf + (long)3 * C_ * C_;

    cvt_all<<<dim3(7296), 256, 0, stream>>>(x, w_qkv, w_proj, x_bf, wqkv_bf, wproj_bf);
    gemm_bt<0><<<dim3(128, 18), 256, 0, stream>>>(x_bf, wqkv_bf, nullptr, q_ws, k_ws, v_ws, nullptr);
    attn_fused<<<dim3(8, 192), 256, 0, stream>>>(q_ws, k_ws, v_ws, o_ws);
    gemm_bt<1><<<dim3(128, 6), 256, 0, stream>>>(o_ws, wproj_bf, b_proj, nullptr, nullptr, nullptr, out);
}